// Round 20
// baseline (197.293 us; speedup 1.0000x reference)
//
#include <hip/hip_runtime.h>
#include <hip/hip_bf16.h>

#define NB 8
#define NN 10000
#define NROW 10001        // y rows per graph (row NN = zero row for csr padding)
#define NE 320000
#define NF 128
#define NH 128
#define RNG 32            // node ranges (buckets) per graph
#define RS 313            // ceil(NN/RNG)
#define BCAP 12288        // csr per-bucket capacity; padded mean 10470 -> +18 sigma
#define NCHUNK 128        // pass-1 chunks per graph
#define P1E 2500          // edges per pass-1 block (NE/NCHUNK)
#define P1CAP 160         // slots per (bucket,chunk); mean 78, sigma 8.7 -> +9.4 sigma
#define ZOFF (NN << 8)    // byte offset of the zero row (within a graph's y slice)

typedef __attribute__((ext_vector_type(8))) _Float16 half8;
typedef __attribute__((ext_vector_type(4))) float f32x4;

// ---------------- ws layout (float indices into ws) ----------------
// [0,        80000)      dinv    (NB*NN f32)
// [80000,   160000)      deg     (NB*NN i32)
// [160000,  160016)      flag    (i32 edge-dtype detect)
// [160016,  1440016)     (unused; was mask — now computed inline in agg<1>)
// [1440016, 1520016)     offs    (NB*NN i32, ABSOLUTE index into csr)
// [1520016, 1552784)     counts  (NB*RNG*NCHUNK i32 per-chunk bucket counts)
// [1552784, 6795664)     gbucket (NB*RNG*NCHUNK*P1CAP u32 packed col<<14|row)
// [6795664, 9941392)     csr     (NB*RNG*BCAP i32 BYTE offsets row*256, quad-padded)
// [9941392, 15062416)    y       (NB*NROW*NH bf16, row NN of each graph = zeros)

__device__ __forceinline__ int load_edge_nt(const int* ei, size_t idx, int is64) {
    if (is64) return (int)__builtin_nontemporal_load(((const long long*)ei) + idx);
    return __builtin_nontemporal_load(ei + idx);
}

__device__ __forceinline__ unsigned short f2bf(float x) {
    __hip_bfloat16 h = __float2bfloat16(x);   // RNE
    return *reinterpret_cast<unsigned short*>(&h);
}

// unpack uint4 = 8 bf16 (low ushort first) into 8-float accumulator
__device__ __forceinline__ void bf8_add(float* a, uint4 u) {
    union { unsigned q; float f; } t;
    t.q = u.x << 16;         a[0] += t.f;
    t.q = u.x & 0xffff0000u; a[1] += t.f;
    t.q = u.y << 16;         a[2] += t.f;
    t.q = u.y & 0xffff0000u; a[3] += t.f;
    t.q = u.z << 16;         a[4] += t.f;
    t.q = u.z & 0xffff0000u; a[5] += t.f;
    t.q = u.w << 16;         a[6] += t.f;
    t.q = u.w & 0xffff0000u; a[7] += t.f;
}

// JAX threefry2x32, partitionable path: counter i -> (hi=0, lo=i), key (0,42),
// out = x0 ^ x1; keep <=> MSB==0 -> scale 2.0 else 0.0. (Bit-identical to the
// old mask_kernel — fused into agg<1> epilogue, r20.)
__device__ __forceinline__ float tf_scale(unsigned i) {
    const unsigned ks0 = 0u, ks1 = 42u, ks2 = 0x1BD11BDAu ^ 0u ^ 42u;
    unsigned x0 = 0u + ks0;
    unsigned x1 = i + ks1;
#define TFR(r) { x0 += x1; x1 = (x1 << (r)) | (x1 >> (32 - (r))); x1 ^= x0; }
    TFR(13) TFR(15) TFR(26) TFR(6)
    x0 += ks1; x1 += ks2 + 1u;
    TFR(17) TFR(29) TFR(16) TFR(24)
    x0 += ks2; x1 += ks0 + 2u;
    TFR(13) TFR(15) TFR(26) TFR(6)
    x0 += ks0; x1 += ks1 + 3u;
    TFR(17) TFR(29) TFR(16) TFR(24)
    x0 += ks1; x1 += ks2 + 4u;
    TFR(13) TFR(15) TFR(26) TFR(6)
    x0 += ks2; x1 += ks0 + 5u;
#undef TFR
    return ((x0 ^ x1) & 0x80000000u) ? 0.0f : 2.0f;
}

// detect edge dtype; also zero each graph's y padding row (row NN).
__global__ void detect_kernel(const int* __restrict__ ei, int* __restrict__ flag,
                              unsigned short* __restrict__ y) {
    __shared__ int s;
    if (threadIdx.x == 0) s = 1;
    for (int i = threadIdx.x; i < NB * 64; i += 256) {   // 8 rows x 64 dwords
        int g = i >> 6, j = i & 63;
        unsigned* zr = (unsigned*)(y + ((size_t)g * NROW + NN) * NH);
        zr[j] = 0u;
    }
    __syncthreads();
    int bad = 0;
    for (int q = threadIdx.x; q < 1024; q += 256)
        if (ei[2 * q + 1] != 0) bad = 1;
    if (bad) atomicAnd(&s, 0);
    __syncthreads();
    if (threadIdx.x == 0) *flag = s;   // 1 => int64 layout
}

// Pass 1, deterministic placement (r17, verified): block (b,chunk) owns fixed
// slot range gbucket[b][bk][chunk][P1CAP] — zero global atomics. bbuf padded
// (stride%32==1) so random-bucket stores spread banks.
__global__ __launch_bounds__(256) void part_kernel(const int* __restrict__ ei,
                                                   const int* __restrict__ flag,
                                                   int* __restrict__ counts,
                                                   unsigned* __restrict__ gbucket) {
    int b = blockIdx.x & 7;                       // graph (XCD-local)
    int chunk = blockIdx.x >> 3;                  // 0..127
    int e0 = chunk * P1E;
    __shared__ int bcnt[RNG];
    __shared__ unsigned bbuf[RNG][P1CAP + 1];     // pad -> bank spread
    if (threadIdx.x < RNG) bcnt[threadIdx.x] = 0;
    __syncthreads();
    int is64 = *flag;
    size_t base = (size_t)b * 2 * NE;
    for (int e = e0 + threadIdx.x; e < e0 + P1E; e += 256) {
        int row = load_edge_nt(ei, base + e, is64);
        int col = load_edge_nt(ei, base + NE + e, is64);
        int bk = col / RS;                        // magic-mul division
        unsigned pk = ((unsigned)col << 14) | (unsigned)row;
        int p = atomicAdd(&bcnt[bk], 1);
        if (p < P1CAP) bbuf[bk][p] = pk;          // overflow: +9.4 sigma, never
    }
    __syncthreads();
    if (threadIdx.x < RNG) {
        int c = bcnt[threadIdx.x];
        counts[(b * RNG + threadIdx.x) * NCHUNK + chunk] = c < P1CAP ? c : P1CAP;
    }
    int wave = threadIdx.x >> 6, lane = threadIdx.x & 63;
    for (int bk = wave; bk < RNG; bk += 4) {
        int len = bcnt[bk]; if (len > P1CAP) len = P1CAP;
        unsigned* dst = gbucket + ((size_t)(b * RNG + bk) * NCHUNK + chunk) * P1CAP;
        for (int i = lane; i < len; i += 64) dst[i] = bbuf[bk][i];
    }
}

// Pass 2: one block per (graph,range). Masked (chunk,slot) domain over the
// chunk-strided bucket segments (L2-hot); LDS hist -> scan over QUAD-PADDED
// counts -> scatter -> pad slots with ZOFF (zero row) -> coalesced copy-out.
// csr = PRE-SCALED BYTE OFFSETS (row*256). deg/dinv stay exact.
__global__ __launch_bounds__(512) void build_kernel(const unsigned* __restrict__ gbucket,
                                                    const int* __restrict__ counts,
                                                    int* __restrict__ csr,
                                                    int* __restrict__ deg,
                                                    int* __restrict__ offs,
                                                    float* __restrict__ dinv) {
    int b = blockIdx.x & 7;
    int r = blockIdx.x >> 3;                      // 0..31
    int n0 = r * RS;
    int nloc = (NN - n0 < RS) ? (NN - n0) : RS;
    __shared__ int lcnt[NCHUNK];
    __shared__ int cnt[512];
    __shared__ int cur[RS];
    __shared__ int buf[BCAP];
    int gidx = b * RNG + r;
    const unsigned* src = gbucket + (size_t)gidx * NCHUNK * P1CAP;
    int t = threadIdx.x;
    if (t < NCHUNK) lcnt[t] = counts[gidx * NCHUNK + t];
    cnt[t] = 0;
    __syncthreads();
    for (int idx = t; idx < NCHUNK * P1CAP; idx += 512) {   // pass 1: hist
        int c = idx / P1CAP, s = idx - c * P1CAP;
        if (s < lcnt[c])
            atomicAdd(&cnt[(src[(size_t)c * P1CAP + s] >> 14) - n0], 1);
    }
    __syncthreads();
    int v = cnt[t];                               // exact degree
    int vp = (v + 3) & ~3;                        // quad-padded length
    __syncthreads();
    // Hillis-Steele inclusive scan over padded lengths
    int x = vp;
    cnt[t] = x;
    __syncthreads();
    for (int off = 1; off < 512; off <<= 1) {
        int add = (t >= off) ? cnt[t - off] : 0;
        __syncthreads();
        x += add;
        cnt[t] = x;
        __syncthreads();
    }
    int K = cnt[511];                             // total padded entries
    int excl = x - vp;
    if (t < nloc) {
        deg[b * NN + n0 + t] = v;
        offs[b * NN + n0 + t] = gidx * BCAP + excl;   // absolute into csr
        dinv[b * NN + n0 + t] = 1.0f / sqrtf((float)(v + 1));  // +1 self-loop
        cur[t] = excl;
    }
    __syncthreads();
    for (int idx = t; idx < NCHUNK * P1CAP; idx += 512) {   // pass 2: scatter
        int c = idx / P1CAP, s = idx - c * P1CAP;
        if (s < lcnt[c]) {
            unsigned pk = src[(size_t)c * P1CAP + s];
            int p = atomicAdd(&cur[(pk >> 14) - n0], 1);
            if (p < BCAP) buf[p] = (int)((pk & 16383u) << 8);  // row*256 bytes
        }
    }
    // pad [excl+v, excl+vp) with the zero-row offset (disjoint from all
    // scatter targets -> safe to run while other threads still scatter)
    if (t < nloc) {
        for (int p = excl + v; p < excl + vp && p < BCAP; ++p) buf[p] = ZOFF;
    }
    __syncthreads();
    int lim = K < BCAP ? K : BCAP;
    int* dstc = csr + (size_t)gidx * BCAP;
    for (int i = t; i < lim; i += 512) dstc[i] = buf[i];   // coalesced
}

// y = bf16[(X @ W) * dinv[row]] via fp16 MFMA (no fp32 MFMA on CDNA4; fp16
// input rounding adds ~3e-4 RMS/layer). Block = 4 waves x 16 rows.
// C/D mapping (HW-verified): col = lane&15, row = (lane>>4)*4 + reg.
// y rows strided NROW per graph (row NN = zero row, untouched here).
__global__ __launch_bounds__(256) void gemm_mfma(const float* __restrict__ X,
                                                 const float* __restrict__ Wm,
                                                 const float* __restrict__ dinv,
                                                 unsigned short* __restrict__ y) {
    __shared__ _Float16 WT[128][136];
    int b = blockIdx.x & 7;
    int row0 = (blockIdx.x >> 3) * 64;
    int t = threadIdx.x;
    for (int e = t; e < 16384; e += 256) {        // stage W^T (fp32->fp16)
        int k = e >> 7, c = e & 127;
        WT[c][k] = (_Float16)Wm[e];
    }
    __syncthreads();

    int lane = t & 63;
    int wrow = row0 + (t >> 6) * 16;              // this wave's 16 output rows
    int r = lane & 15;                            // A-row / B-col / D-col
    int g = lane >> 4;                            // k-group
    const float* Xb = X + (size_t)b * NN * NF;
    int grow = wrow + r;

    f32x4 acc[8] = {};
#pragma unroll
    for (int kk = 0; kk < 4; ++kk) {
        half8 a;
        if (grow < NN) {
            const float* px = Xb + (size_t)grow * NF + kk * 32 + g * 8;
            float4 x0 = *(const float4*)px;
            float4 x1 = *(const float4*)(px + 4);
            a[0] = (_Float16)x0.x; a[1] = (_Float16)x0.y;
            a[2] = (_Float16)x0.z; a[3] = (_Float16)x0.w;
            a[4] = (_Float16)x1.x; a[5] = (_Float16)x1.y;
            a[6] = (_Float16)x1.z; a[7] = (_Float16)x1.w;
        } else {
            a = (half8)(_Float16)0.0f;
        }
#pragma unroll
        for (int c = 0; c < 8; ++c) {
            half8 bf = *(const half8*)&WT[c * 16 + r][kk * 32 + g * 8];
            acc[c] = __builtin_amdgcn_mfma_f32_16x16x32_f16(a, bf, acc[c], 0, 0, 0);
        }
    }

#pragma unroll
    for (int i = 0; i < 4; ++i) {
        int orow = wrow + g * 4 + i;
        if (orow >= NN) continue;
        float d = dinv[b * NN + orow];
        unsigned short* yp = y + ((size_t)b * NROW + orow) * NH + r;
#pragma unroll
        for (int c = 0; c < 8; ++c)
            yp[c * 16] = f2bf(acc[c][i] * d);
    }
}

// Gather-reduce, quarter-wave, two node-streams, quad-padded csr (r19 form).
// r20: dropout mask computed INLINE via threefry (tf_scale) in the LAYER==1
// epilogue — deletes the mask_kernel dispatch and agg<1>'s mask reads.
template<int LAYER>
__global__ __launch_bounds__(256) void aggregate_full(const unsigned short* __restrict__ y,
                                                      const int* __restrict__ offs,
                                                      const int* __restrict__ deg,
                                                      const int* __restrict__ csr,
                                                      const float* __restrict__ dinv,
                                                      const float* __restrict__ bias,
                                                      float* __restrict__ out) {
    int b = blockIdx.x & 7;
    int w = threadIdx.x >> 6;
    int idx = (blockIdx.x >> 3) * 4 + w;     // [0, 5000)
    int n0 = idx, n1 = idx + 5000;
    int lane = threadIdx.x & 63;
    int q = lane >> 4;                       // quarter: which edge of a group of 4
    unsigned q16 = (unsigned)(lane & 15) * 16u;     // byte offset of feat octet
    const char* ybc = (const char*)(y + (size_t)b * NROW * NH);  // wave-uniform base

    float a0[8] = {0.f,0.f,0.f,0.f,0.f,0.f,0.f,0.f};
    float a1[8] = {0.f,0.f,0.f,0.f,0.f,0.f,0.f,0.f};
    if (q == 0) {   // self-loop, counted once
        uint4 s0 = *(const uint4*)(ybc + (unsigned)n0 * 256u + q16);
        uint4 s1 = *(const uint4*)(ybc + (unsigned)n1 * 256u + q16);
        bf8_add(a0, s0);
        bf8_add(a1, s1);
    }

    const int* ob = offs + b * NN;
    const int* db = deg + b * NN;
    int ba = ob[n0], o1a = ba + ((db[n0] + 3) & ~3);
    int bb = ob[n1], o1b = bb + ((db[n1] + 3) & ~3);

#define PROCQ(r_, j_, acc_) { \
    unsigned o = (unsigned)__shfl((r_), (j_) + q); \
    uint4 u = *(const uint4*)(ybc + o + q16); \
    bf8_add(acc_, u); \
}

    while (ba < o1a || bb < o1b) {
        int ma = o1a - ba; ma = ma < 0 ? 0 : (ma > 64 ? 64 : ma);   // mult of 4
        int mb = o1b - bb; mb = mb < 0 ? 0 : (mb > 64 ? 64 : mb);   // mult of 4
        int ra = (lane < ma) ? csr[ba + lane] : 0;   // byte offsets
        int rb = (lane < mb) ? csr[bb + lane] : 0;
        int mmin = ma < mb ? ma : mb;
        int jj = 0;
#pragma unroll 4
        for (; jj < mmin; jj += 4) {                 // 8 loads in flight
            PROCQ(ra, jj, a0)
            PROCQ(rb, jj, a1)
        }
#pragma unroll 2
        for (int ja = jj; ja < ma; ja += 4) PROCQ(ra, ja, a0)
#pragma unroll 2
        for (int jb = jj; jb < mb; jb += 4) PROCQ(rb, jb, a1)
        ba += 64; bb += 64;
    }
#undef PROCQ

    // merge the 4 edge-quarters (lanes with equal lane&15 hold same feats)
#pragma unroll
    for (int i = 0; i < 8; ++i) {
        a0[i] += __shfl_xor(a0[i], 16);
        a0[i] += __shfl_xor(a0[i], 32);
        a1[i] += __shfl_xor(a1[i], 16);
        a1[i] += __shfl_xor(a1[i], 32);
    }

    // quarter 0 writes n0, quarter 1 writes n1 (16 lanes x 32B contiguous)
    if (q < 2) {
        int n = q ? n1 : n0;
        float av[8];
#pragma unroll
        for (int i = 0; i < 8; ++i) av[i] = q ? a1[i] : a0[i];
        float d = dinv[b * NN + n];
        unsigned f0 = (lane & 15) * 8;           // first feature of octet
        float4 bi0 = *(const float4*)(bias + f0);
        float4 bi1 = *(const float4*)(bias + f0 + 4);
        float o[8];
        o[0] = fmaf(d, av[0], bi0.x);
        o[1] = fmaf(d, av[1], bi0.y);
        o[2] = fmaf(d, av[2], bi0.z);
        o[3] = fmaf(d, av[3], bi0.w);
        o[4] = fmaf(d, av[4], bi1.x);
        o[5] = fmaf(d, av[5], bi1.y);
        o[6] = fmaf(d, av[6], bi1.z);
        o[7] = fmaf(d, av[7], bi1.w);
        if (LAYER == 1) {
            unsigned base_i = (unsigned)n * NH + f0;
#pragma unroll
            for (int i = 0; i < 8; ++i)
                o[i] = fmaxf(o[i], 0.f) * tf_scale(base_i + i);
        }
        float* op = out + ((size_t)b * NN + n) * NH + f0;
        *(float4*)op       = make_float4(o[0], o[1], o[2], o[3]);
        *(float4*)(op + 4) = make_float4(o[4], o[5], o[6], o[7]);
    }
}

extern "C" void kernel_launch(void* const* d_in, const int* in_sizes, int n_in,
                              void* d_out, int out_size, void* d_ws, size_t ws_size,
                              hipStream_t stream) {
    const float* xs = (const float*)d_in[0];
    const int*   ei = (const int*)d_in[1];
    const float* W1 = (const float*)d_in[2];
    const float* b1 = (const float*)d_in[3];
    const float* W2 = (const float*)d_in[4];
    const float* b2 = (const float*)d_in[5];
    float* out = (float*)d_out;

    float* ws        = (float*)d_ws;
    float* dinv      = ws;
    int*   deg       = (int*)(ws + 80000);
    int*   flag      = (int*)(ws + 160000);
    int*   offs      = (int*)(ws + 1440016);
    int*   counts    = (int*)(ws + 1520016);
    unsigned* gbucket= (unsigned*)(ws + 1552784);
    int*   csr       = (int*)(ws + 6795664);
    unsigned short* y= (unsigned short*)(ws + 9941392);

    detect_kernel<<<1, 256, 0, stream>>>(ei, flag, y);
    part_kernel<<<NB * NCHUNK, 256, 0, stream>>>(ei, flag, counts, gbucket);
    build_kernel<<<NB * RNG, 512, 0, stream>>>(gbucket, counts, csr, deg, offs, dinv);

    dim3 gemm_grid(8 * ((NN + 63) / 64));   // blockIdx&7 = graph (XCD-local)
    dim3 agg_grid(NB * (5000 / 4));         // 10000 blocks, 4 waves x 2 nodes each

    // Layer 1: h -> d_out (dropout mask computed inline via threefry)
    gemm_mfma<<<gemm_grid, 256, 0, stream>>>(xs, W1, dinv, y);
    aggregate_full<1><<<agg_grid, 256, 0, stream>>>(y, offs, deg, csr, dinv, b1, out);

    // Layer 2: reads h from d_out into y, then overwrites d_out
    gemm_mfma<<<gemm_grid, 256, 0, stream>>>(out, W2, dinv, y);
    aggregate_full<2><<<agg_grid, 256, 0, stream>>>(y, offs, deg, csr, dinv, b2, out);
}

// Round 21
// 180.337 us; speedup vs baseline: 1.0940x; 1.0940x over previous
//
#include <hip/hip_runtime.h>
#include <hip/hip_bf16.h>

#define NB 8
#define NN 10000
#define NROW 10001        // y rows per graph (row NN = zero row for csr padding)
#define NE 320000
#define NF 128
#define NH 128
#define RNG 32            // node ranges (buckets) per graph
#define RS 313            // ceil(NN/RNG)
#define BCAP 12288        // csr per-bucket capacity; padded mean 10470 -> +18 sigma
#define NCHUNK 128        // pass-1 chunks per graph
#define P1E 2500          // edges per pass-1 block (NE/NCHUNK)
#define P1CAP 160         // slots per (bucket,chunk); mean 78, sigma 8.7 -> +9.4 sigma
#define ZOFF (NN << 8)    // byte offset of the zero row (within a graph's y slice)

typedef __attribute__((ext_vector_type(8))) _Float16 half8;
typedef __attribute__((ext_vector_type(4))) float f32x4;

// ---------------- ws layout (float indices into ws) ----------------
// [0,        80000)      dinv    (NB*NN f32)
// [80000,   160000)      deg     (NB*NN i32)
// [160000,  160016)      flag    (i32 edge-dtype detect)
// [160016,  1440016)     mask    (NN*NH f32: 0.0 or 2.0; written by part_kernel)
// [1440016, 1520016)     offs    (NB*NN i32, ABSOLUTE index into csr)
// [1520016, 1552784)     counts  (NB*RNG*NCHUNK i32 per-chunk bucket counts)
// [1552784, 6795664)     gbucket (NB*RNG*NCHUNK*P1CAP u32 packed col<<14|row)
// [6795664, 9941392)     csr     (NB*RNG*BCAP i32 BYTE offsets row*256, quad-padded)
// [9941392, 15062416)    y       (NB*NROW*NH bf16, row NN of each graph = zeros)

__device__ __forceinline__ int load_edge_nt(const int* ei, size_t idx, int is64) {
    if (is64) return (int)__builtin_nontemporal_load(((const long long*)ei) + idx);
    return __builtin_nontemporal_load(ei + idx);
}

__device__ __forceinline__ unsigned short f2bf(float x) {
    __hip_bfloat16 h = __float2bfloat16(x);   // RNE
    return *reinterpret_cast<unsigned short*>(&h);
}

// unpack uint4 = 8 bf16 (low ushort first) into 8-float accumulator
__device__ __forceinline__ void bf8_add(float* a, uint4 u) {
    union { unsigned q; float f; } t;
    t.q = u.x << 16;         a[0] += t.f;
    t.q = u.x & 0xffff0000u; a[1] += t.f;
    t.q = u.y << 16;         a[2] += t.f;
    t.q = u.y & 0xffff0000u; a[3] += t.f;
    t.q = u.z << 16;         a[4] += t.f;
    t.q = u.z & 0xffff0000u; a[5] += t.f;
    t.q = u.w << 16;         a[6] += t.f;
    t.q = u.w & 0xffff0000u; a[7] += t.f;
}

// JAX threefry2x32, partitionable path: counter i -> (hi=0, lo=i), key (0,42),
// out = x0 ^ x1; keep <=> MSB==0 -> scale 2.0 else 0.0.
// r20 lesson: mask is BATCH-INVARIANT (1.28M hashes once) — computing it
// per-(graph,node) in agg<1>'s epilogue was 8x redundant and VALU-bound
// (agg<1> 55->79us, VALUBusy 80%). Compute once, in part_kernel's shadow.
__device__ __forceinline__ float tf_scale(unsigned i) {
    const unsigned ks0 = 0u, ks1 = 42u, ks2 = 0x1BD11BDAu ^ 0u ^ 42u;
    unsigned x0 = 0u + ks0;
    unsigned x1 = i + ks1;
#define TFR(r) { x0 += x1; x1 = (x1 << (r)) | (x1 >> (32 - (r))); x1 ^= x0; }
    TFR(13) TFR(15) TFR(26) TFR(6)
    x0 += ks1; x1 += ks2 + 1u;
    TFR(17) TFR(29) TFR(16) TFR(24)
    x0 += ks2; x1 += ks0 + 2u;
    TFR(13) TFR(15) TFR(26) TFR(6)
    x0 += ks0; x1 += ks1 + 3u;
    TFR(17) TFR(29) TFR(16) TFR(24)
    x0 += ks1; x1 += ks2 + 4u;
    TFR(13) TFR(15) TFR(26) TFR(6)
    x0 += ks2; x1 += ks0 + 5u;
#undef TFR
    return ((x0 ^ x1) & 0x80000000u) ? 0.0f : 2.0f;
}

// detect edge dtype; also zero each graph's y padding row (row NN).
__global__ void detect_kernel(const int* __restrict__ ei, int* __restrict__ flag,
                              unsigned short* __restrict__ y) {
    __shared__ int s;
    if (threadIdx.x == 0) s = 1;
    for (int i = threadIdx.x; i < NB * 64; i += 256) {   // 8 rows x 64 dwords
        int g = i >> 6, j = i & 63;
        unsigned* zr = (unsigned*)(y + ((size_t)g * NROW + NN) * NH);
        zr[j] = 0u;
    }
    __syncthreads();
    int bad = 0;
    for (int q = threadIdx.x; q < 1024; q += 256)
        if (ei[2 * q + 1] != 0) bad = 1;
    if (bad) atomicAnd(&s, 0);
    __syncthreads();
    if (threadIdx.x == 0) *flag = s;   // 1 => int64 layout
}

// Pass 1, deterministic placement (r17, verified): block (b,chunk) owns fixed
// slot range gbucket[b][bk][chunk][P1CAP] — zero global atomics. bbuf padded
// (stride%32==1) so random-bucket stores spread banks.
// r21: dropout mask fused here (262K threads x ~5 threefry hashes each,
// ~1.8us machine-wide VALU hidden under this kernel's memory latency) —
// deletes the standalone mask_kernel dispatch.
__global__ __launch_bounds__(256) void part_kernel(const int* __restrict__ ei,
                                                   const int* __restrict__ flag,
                                                   int* __restrict__ counts,
                                                   unsigned* __restrict__ gbucket,
                                                   float* __restrict__ mask) {
    int b = blockIdx.x & 7;                       // graph (XCD-local)
    int chunk = blockIdx.x >> 3;                  // 0..127
    int e0 = chunk * P1E;
    __shared__ int bcnt[RNG];
    __shared__ unsigned bbuf[RNG][P1CAP + 1];     // pad -> bank spread
    if (threadIdx.x < RNG) bcnt[threadIdx.x] = 0;
    __syncthreads();
    int is64 = *flag;
    size_t base = (size_t)b * 2 * NE;
    for (int e = e0 + threadIdx.x; e < e0 + P1E; e += 256) {
        int row = load_edge_nt(ei, base + e, is64);
        int col = load_edge_nt(ei, base + NE + e, is64);
        int bk = col / RS;                        // magic-mul division
        unsigned pk = ((unsigned)col << 14) | (unsigned)row;
        int p = atomicAdd(&bcnt[bk], 1);
        if (p < P1CAP) bbuf[bk][p] = pk;          // overflow: +9.4 sigma, never
    }
    __syncthreads();
    if (threadIdx.x < RNG) {
        int c = bcnt[threadIdx.x];
        counts[(b * RNG + threadIdx.x) * NCHUNK + chunk] = c < P1CAP ? c : P1CAP;
    }
    int wave = threadIdx.x >> 6, lane = threadIdx.x & 63;
    for (int bk = wave; bk < RNG; bk += 4) {
        int len = bcnt[bk]; if (len > P1CAP) len = P1CAP;
        unsigned* dst = gbucket + ((size_t)(b * RNG + bk) * NCHUNK + chunk) * P1CAP;
        for (int i = lane; i < len; i += 64) dst[i] = bbuf[bk][i];
    }
    // fused mask generation: grid-stride over the 1.28M shared mask elements
    const unsigned MTOT = NN * NH, STRIDE = NB * NCHUNK * 256;
    for (unsigned i = blockIdx.x * 256 + threadIdx.x; i < MTOT; i += STRIDE)
        mask[i] = tf_scale(i);
}

// Pass 2: one block per (graph,range). Masked (chunk,slot) domain over the
// chunk-strided bucket segments (L2-hot); LDS hist -> scan over QUAD-PADDED
// counts -> scatter -> pad slots with ZOFF (zero row) -> coalesced copy-out.
// csr = PRE-SCALED BYTE OFFSETS (row*256). deg/dinv stay exact.
__global__ __launch_bounds__(512) void build_kernel(const unsigned* __restrict__ gbucket,
                                                    const int* __restrict__ counts,
                                                    int* __restrict__ csr,
                                                    int* __restrict__ deg,
                                                    int* __restrict__ offs,
                                                    float* __restrict__ dinv) {
    int b = blockIdx.x & 7;
    int r = blockIdx.x >> 3;                      // 0..31
    int n0 = r * RS;
    int nloc = (NN - n0 < RS) ? (NN - n0) : RS;
    __shared__ int lcnt[NCHUNK];
    __shared__ int cnt[512];
    __shared__ int cur[RS];
    __shared__ int buf[BCAP];
    int gidx = b * RNG + r;
    const unsigned* src = gbucket + (size_t)gidx * NCHUNK * P1CAP;
    int t = threadIdx.x;
    if (t < NCHUNK) lcnt[t] = counts[gidx * NCHUNK + t];
    cnt[t] = 0;
    __syncthreads();
    for (int idx = t; idx < NCHUNK * P1CAP; idx += 512) {   // pass 1: hist
        int c = idx / P1CAP, s = idx - c * P1CAP;
        if (s < lcnt[c])
            atomicAdd(&cnt[(src[(size_t)c * P1CAP + s] >> 14) - n0], 1);
    }
    __syncthreads();
    int v = cnt[t];                               // exact degree
    int vp = (v + 3) & ~3;                        // quad-padded length
    __syncthreads();
    // Hillis-Steele inclusive scan over padded lengths
    int x = vp;
    cnt[t] = x;
    __syncthreads();
    for (int off = 1; off < 512; off <<= 1) {
        int add = (t >= off) ? cnt[t - off] : 0;
        __syncthreads();
        x += add;
        cnt[t] = x;
        __syncthreads();
    }
    int K = cnt[511];                             // total padded entries
    int excl = x - vp;
    if (t < nloc) {
        deg[b * NN + n0 + t] = v;
        offs[b * NN + n0 + t] = gidx * BCAP + excl;   // absolute into csr
        dinv[b * NN + n0 + t] = 1.0f / sqrtf((float)(v + 1));  // +1 self-loop
        cur[t] = excl;
    }
    __syncthreads();
    for (int idx = t; idx < NCHUNK * P1CAP; idx += 512) {   // pass 2: scatter
        int c = idx / P1CAP, s = idx - c * P1CAP;
        if (s < lcnt[c]) {
            unsigned pk = src[(size_t)c * P1CAP + s];
            int p = atomicAdd(&cur[(pk >> 14) - n0], 1);
            if (p < BCAP) buf[p] = (int)((pk & 16383u) << 8);  // row*256 bytes
        }
    }
    // pad [excl+v, excl+vp) with the zero-row offset (disjoint from all
    // scatter targets -> safe to run while other threads still scatter)
    if (t < nloc) {
        for (int p = excl + v; p < excl + vp && p < BCAP; ++p) buf[p] = ZOFF;
    }
    __syncthreads();
    int lim = K < BCAP ? K : BCAP;
    int* dstc = csr + (size_t)gidx * BCAP;
    for (int i = t; i < lim; i += 512) dstc[i] = buf[i];   // coalesced
}

// y = bf16[(X @ W) * dinv[row]] via fp16 MFMA (no fp32 MFMA on CDNA4; fp16
// input rounding adds ~3e-4 RMS/layer). Block = 4 waves x 16 rows.
// C/D mapping (HW-verified): col = lane&15, row = (lane>>4)*4 + reg.
// y rows strided NROW per graph (row NN = zero row, untouched here).
__global__ __launch_bounds__(256) void gemm_mfma(const float* __restrict__ X,
                                                 const float* __restrict__ Wm,
                                                 const float* __restrict__ dinv,
                                                 unsigned short* __restrict__ y) {
    __shared__ _Float16 WT[128][136];
    int b = blockIdx.x & 7;
    int row0 = (blockIdx.x >> 3) * 64;
    int t = threadIdx.x;
    for (int e = t; e < 16384; e += 256) {        // stage W^T (fp32->fp16)
        int k = e >> 7, c = e & 127;
        WT[c][k] = (_Float16)Wm[e];
    }
    __syncthreads();

    int lane = t & 63;
    int wrow = row0 + (t >> 6) * 16;              // this wave's 16 output rows
    int r = lane & 15;                            // A-row / B-col / D-col
    int g = lane >> 4;                            // k-group
    const float* Xb = X + (size_t)b * NN * NF;
    int grow = wrow + r;

    f32x4 acc[8] = {};
#pragma unroll
    for (int kk = 0; kk < 4; ++kk) {
        half8 a;
        if (grow < NN) {
            const float* px = Xb + (size_t)grow * NF + kk * 32 + g * 8;
            float4 x0 = *(const float4*)px;
            float4 x1 = *(const float4*)(px + 4);
            a[0] = (_Float16)x0.x; a[1] = (_Float16)x0.y;
            a[2] = (_Float16)x0.z; a[3] = (_Float16)x0.w;
            a[4] = (_Float16)x1.x; a[5] = (_Float16)x1.y;
            a[6] = (_Float16)x1.z; a[7] = (_Float16)x1.w;
        } else {
            a = (half8)(_Float16)0.0f;
        }
#pragma unroll
        for (int c = 0; c < 8; ++c) {
            half8 bf = *(const half8*)&WT[c * 16 + r][kk * 32 + g * 8];
            acc[c] = __builtin_amdgcn_mfma_f32_16x16x32_f16(a, bf, acc[c], 0, 0, 0);
        }
    }

#pragma unroll
    for (int i = 0; i < 4; ++i) {
        int orow = wrow + g * 4 + i;
        if (orow >= NN) continue;
        float d = dinv[b * NN + orow];
        unsigned short* yp = y + ((size_t)b * NROW + orow) * NH + r;
#pragma unroll
        for (int c = 0; c < 8; ++c)
            yp[c * 16] = f2bf(acc[c][i] * d);
    }
}

// Gather-reduce, quarter-wave, two node-streams, quad-padded csr (r19 form,
// 55us verified). Mask read from the precomputed batch-shared table.
template<int LAYER>
__global__ __launch_bounds__(256) void aggregate_full(const unsigned short* __restrict__ y,
                                                      const int* __restrict__ offs,
                                                      const int* __restrict__ deg,
                                                      const int* __restrict__ csr,
                                                      const float* __restrict__ dinv,
                                                      const float* __restrict__ bias,
                                                      const float* __restrict__ mask,
                                                      float* __restrict__ out) {
    int b = blockIdx.x & 7;
    int w = threadIdx.x >> 6;
    int idx = (blockIdx.x >> 3) * 4 + w;     // [0, 5000)
    int n0 = idx, n1 = idx + 5000;
    int lane = threadIdx.x & 63;
    int q = lane >> 4;                       // quarter: which edge of a group of 4
    unsigned q16 = (unsigned)(lane & 15) * 16u;     // byte offset of feat octet
    const char* ybc = (const char*)(y + (size_t)b * NROW * NH);  // wave-uniform base

    float a0[8] = {0.f,0.f,0.f,0.f,0.f,0.f,0.f,0.f};
    float a1[8] = {0.f,0.f,0.f,0.f,0.f,0.f,0.f,0.f};
    if (q == 0) {   // self-loop, counted once
        uint4 s0 = *(const uint4*)(ybc + (unsigned)n0 * 256u + q16);
        uint4 s1 = *(const uint4*)(ybc + (unsigned)n1 * 256u + q16);
        bf8_add(a0, s0);
        bf8_add(a1, s1);
    }

    const int* ob = offs + b * NN;
    const int* db = deg + b * NN;
    int ba = ob[n0], o1a = ba + ((db[n0] + 3) & ~3);
    int bb = ob[n1], o1b = bb + ((db[n1] + 3) & ~3);

#define PROCQ(r_, j_, acc_) { \
    unsigned o = (unsigned)__shfl((r_), (j_) + q); \
    uint4 u = *(const uint4*)(ybc + o + q16); \
    bf8_add(acc_, u); \
}

    while (ba < o1a || bb < o1b) {
        int ma = o1a - ba; ma = ma < 0 ? 0 : (ma > 64 ? 64 : ma);   // mult of 4
        int mb = o1b - bb; mb = mb < 0 ? 0 : (mb > 64 ? 64 : mb);   // mult of 4
        int ra = (lane < ma) ? csr[ba + lane] : 0;   // byte offsets
        int rb = (lane < mb) ? csr[bb + lane] : 0;
        int mmin = ma < mb ? ma : mb;
        int jj = 0;
#pragma unroll 4
        for (; jj < mmin; jj += 4) {                 // 8 loads in flight
            PROCQ(ra, jj, a0)
            PROCQ(rb, jj, a1)
        }
#pragma unroll 2
        for (int ja = jj; ja < ma; ja += 4) PROCQ(ra, ja, a0)
#pragma unroll 2
        for (int jb = jj; jb < mb; jb += 4) PROCQ(rb, jb, a1)
        ba += 64; bb += 64;
    }
#undef PROCQ

    // merge the 4 edge-quarters (lanes with equal lane&15 hold same feats)
#pragma unroll
    for (int i = 0; i < 8; ++i) {
        a0[i] += __shfl_xor(a0[i], 16);
        a0[i] += __shfl_xor(a0[i], 32);
        a1[i] += __shfl_xor(a1[i], 16);
        a1[i] += __shfl_xor(a1[i], 32);
    }

    // quarter 0 writes n0, quarter 1 writes n1 (16 lanes x 32B contiguous)
    if (q < 2) {
        int n = q ? n1 : n0;
        float av[8];
#pragma unroll
        for (int i = 0; i < 8; ++i) av[i] = q ? a1[i] : a0[i];
        float d = dinv[b * NN + n];
        unsigned f0 = (lane & 15) * 8;           // first feature of octet
        float4 bi0 = *(const float4*)(bias + f0);
        float4 bi1 = *(const float4*)(bias + f0 + 4);
        float4 o0, o1;
        o0.x = fmaf(d, av[0], bi0.x);
        o0.y = fmaf(d, av[1], bi0.y);
        o0.z = fmaf(d, av[2], bi0.z);
        o0.w = fmaf(d, av[3], bi0.w);
        o1.x = fmaf(d, av[4], bi1.x);
        o1.y = fmaf(d, av[5], bi1.y);
        o1.z = fmaf(d, av[6], bi1.z);
        o1.w = fmaf(d, av[7], bi1.w);
        if (LAYER == 1) {
            float4 m0 = *(const float4*)(mask + (size_t)n * NH + f0);
            float4 m1 = *(const float4*)(mask + (size_t)n * NH + f0 + 4);
            o0.x = fmaxf(o0.x, 0.f) * m0.x;
            o0.y = fmaxf(o0.y, 0.f) * m0.y;
            o0.z = fmaxf(o0.z, 0.f) * m0.z;
            o0.w = fmaxf(o0.w, 0.f) * m0.w;
            o1.x = fmaxf(o1.x, 0.f) * m1.x;
            o1.y = fmaxf(o1.y, 0.f) * m1.y;
            o1.z = fmaxf(o1.z, 0.f) * m1.z;
            o1.w = fmaxf(o1.w, 0.f) * m1.w;
        }
        float* op = out + ((size_t)b * NN + n) * NH + f0;
        *(float4*)op = o0;
        *(float4*)(op + 4) = o1;
    }
}

extern "C" void kernel_launch(void* const* d_in, const int* in_sizes, int n_in,
                              void* d_out, int out_size, void* d_ws, size_t ws_size,
                              hipStream_t stream) {
    const float* xs = (const float*)d_in[0];
    const int*   ei = (const int*)d_in[1];
    const float* W1 = (const float*)d_in[2];
    const float* b1 = (const float*)d_in[3];
    const float* W2 = (const float*)d_in[4];
    const float* b2 = (const float*)d_in[5];
    float* out = (float*)d_out;

    float* ws        = (float*)d_ws;
    float* dinv      = ws;
    int*   deg       = (int*)(ws + 80000);
    int*   flag      = (int*)(ws + 160000);
    float* mask      = ws + 160016;
    int*   offs      = (int*)(ws + 1440016);
    int*   counts    = (int*)(ws + 1520016);
    unsigned* gbucket= (unsigned*)(ws + 1552784);
    int*   csr       = (int*)(ws + 6795664);
    unsigned short* y= (unsigned short*)(ws + 9941392);

    detect_kernel<<<1, 256, 0, stream>>>(ei, flag, y);
    part_kernel<<<NB * NCHUNK, 256, 0, stream>>>(ei, flag, counts, gbucket, mask);
    build_kernel<<<NB * RNG, 512, 0, stream>>>(gbucket, counts, csr, deg, offs, dinv);

    dim3 gemm_grid(8 * ((NN + 63) / 64));   // blockIdx&7 = graph (XCD-local)
    dim3 agg_grid(NB * (5000 / 4));         // 10000 blocks, 4 waves x 2 nodes each

    // Layer 1: h -> d_out
    gemm_mfma<<<gemm_grid, 256, 0, stream>>>(xs, W1, dinv, y);
    aggregate_full<1><<<agg_grid, 256, 0, stream>>>(y, offs, deg, csr, dinv, b1, mask, out);

    // Layer 2: reads h from d_out into y, then overwrites d_out
    gemm_mfma<<<gemm_grid, 256, 0, stream>>>(out, W2, dinv, y);
    aggregate_full<2><<<agg_grid, 256, 0, stream>>>(y, offs, deg, csr, dinv, b2, nullptr, out);
}